// Round 7
// baseline (386.967 us; speedup 1.0000x reference)
//
#include <hip/hip_runtime.h>
#include <math.h>

#define L_  12
#define B_  32
#define H_  12
#define N1_ 197
#define D_  768
#define R_  19
#define M_TOK (B_ * N1_)               // 6304
#define NN (N1_ * N1_)                 // 38809

// mega1: k1v2 blocks + pack blocks
#define K1_LB_BLOCKS  (11 * 32 * 50)   // 17600 (50 blocks per (l,b), 4 rows each)
#define K1V2_BLOCKS   (K1_LB_BLOCKS + 32)  // + layer-11 row-0 per b = 17632
#define PACK_ROWS     (M_TOK + 2304)   // x rows + [k;v;q] weight rows = 8608
#define PACK_BLOCKS   ((PACK_ROWS * 24 + 255) / 256)   // 807
#define MEGA1_BLOCKS  (K1V2_BLOCKS + PACK_BLOCKS)

// mega2: QKV gemm tiles + k2 chain blocks
#define QKV_TILES     900              // 50 x 18 (M=6304, N=2304)
#define MEGA2_BLOCKS  (QKV_TILES + B_) // + 32 chain blocks

typedef __attribute__((ext_vector_type(8))) short short8;
typedef __attribute__((ext_vector_type(4))) float f32x4;

__device__ __forceinline__ f32x4 ld4u(const float* p) {
  f32x4 r; __builtin_memcpy(&r, p, 16); return r;
}
__device__ __forceinline__ void st4u(float* p, f32x4 v) {
  __builtin_memcpy(p, &v, 16);
}

// f32 -> bf16 hi/lo split. hi = rn(f), lo = rn(f - hi); hh+hl+lh ~ f32 product.
__device__ inline ushort f2bf_rn(float f) {
  unsigned u = __float_as_uint(f);
  unsigned r = (u + 0x7FFFu + ((u >> 16) & 1u)) >> 16;
  return (ushort)r;
}
__device__ inline float bf2f(ushort h) { return __uint_as_float((unsigned)h << 16); }
__device__ inline void cvt4(float4 f, ushort4& h, ushort4& l) {
  h.x = f2bf_rn(f.x); l.x = f2bf_rn(f.x - bf2f(h.x));
  h.y = f2bf_rn(f.y); l.y = f2bf_rn(f.y - bf2f(h.y));
  h.z = f2bf_rn(f.z); l.z = f2bf_rn(f.z - bf2f(h.z));
  h.w = f2bf_rn(f.w); l.w = f2bf_rn(f.w - bf2f(h.w));
}

typedef const __attribute__((address_space(1))) void* as1_vp;
typedef __attribute__((address_space(3))) void* as3_vp;
__device__ __forceinline__ void gl_lds16(const void* g, void* s) {
  __builtin_amdgcn_global_load_lds((as1_vp)g, (as3_vp)s, 16, 0, 0);
}

// ---------------------------------------------------------------------------
// MEGA1:
//  blocks [0, K1V2_BLOCKS): k1v2 — block owns nrows (<=4) CONSECUTIVE rows of
//   one (l,b). Thread t accumulates float4 at byte 16t of the contiguous
//   nrows*788-B window across 12 heads (each load instr = up to 3152B dense
//   burst, 1 stream/block). Then LDS row-reduce -> rowsum -> normalize -> P.
//   Layers 0..10 all rows; layer 11 row 0 only (chain needs only e0^T A[11]).
//  blocks [K1V2_BLOCKS, +PACK_BLOCKS): pack x,[k_w;v_w;q_w] -> bf16 hi/lo
//   [row][24][hi32|lo32] (128B per (row,kb)).
// ---------------------------------------------------------------------------
__global__ __launch_bounds__(256) void mega1_k1_pack(const float* __restrict__ attn,
                                                     float* __restrict__ P,
                                                     float* __restrict__ dvec,
                                                     const float* __restrict__ x,
                                                     const float* __restrict__ k_w,
                                                     const float* __restrict__ v_w,
                                                     const float* __restrict__ q_w,
                                                     ushort* __restrict__ xpack,
                                                     ushort* __restrict__ wpack) {
  int bid = blockIdx.x;
  if (bid < K1V2_BLOCKS) {
    __shared__ float lrow[800];
    int l, b, i0, nrows;
    if (bid < K1_LB_BLOCKS) {
      int lb  = bid / 50;
      int sub = bid - lb * 50;
      l = lb >> 5; b = lb & 31;
      i0 = sub * 4;
      nrows = (i0 + 4 <= N1_) ? 4 : (N1_ - i0);   // sub==49 -> 1 row
    } else {
      l = 11; b = bid - K1_LB_BLOCKS; i0 = 0; nrows = 1;
    }
    int lbi = l * B_ + b;
    const float* base = attn + (size_t)lbi * (H_ * NN) + (size_t)i0 * N1_;
    int W = nrows * N1_;                          // 788 or 197
    int t = threadIdx.x;
    f32x4 acc = {0.f, 0.f, 0.f, 0.f};
    if (4 * t + 4 <= W) {
      const float* p = base + 4 * t;
#pragma unroll
      for (int h = 0; h < H_; ++h) acc += ld4u(p + (size_t)h * NN);
    } else if (4 * t < W) {                       // partial tail (rem elems)
      const float* p = base + 4 * t;
      int rem = W - 4 * t;
#pragma unroll
      for (int h = 0; h < H_; ++h) {
        const float* ph = p + (size_t)h * NN;
        for (int e = 0; e < rem; ++e) acc[e] += ph[e];
      }
    }
    if (4 * t < W) {
      lrow[4 * t]     = acc.x;
      lrow[4 * t + 1] = acc.y;
      lrow[4 * t + 2] = acc.z;
      lrow[4 * t + 3] = acc.w;
    }
    __syncthreads();
    int wv = t >> 6, ln = t & 63;
    if (wv < nrows) {
      int rb = N1_ * wv;
      float s0 = 0.f, s1 = 0.f, s2 = 0.f, s3 = 0.f;
      if (ln < 49) {
        s0 = lrow[rb + 4 * ln];     s1 = lrow[rb + 4 * ln + 1];
        s2 = lrow[rb + 4 * ln + 2]; s3 = lrow[rb + 4 * ln + 3];
      } else if (ln == 49) {
        s0 = lrow[rb + 196];
      }
      float s = (s0 + s1) + (s2 + s3);
#pragma unroll
      for (int o = 32; o; o >>= 1) s += __shfl_xor(s, o);
      float inv = 1.f / (s + 12.f);
      int prow = lbi * N1_ + i0 + wv;
      float* Pr = P + (size_t)prow * N1_;
      if (ln < 49) {
        f32x4 vv = {s0 * inv, s1 * inv, s2 * inv, s3 * inv};
        st4u(Pr + 4 * ln, vv);
      } else if (ln == 49) {
        Pr[196] = s0 * inv;
      }
      if (ln == 0) dvec[prow] = 12.f * inv;
    }
  } else {
    int t = (bid - K1V2_BLOCKS) * 256 + threadIdx.x;
    if (t >= PACK_ROWS * 24) return;
    int row = t / 24, kb = t - row * 24;
    const float* src;
    ushort* dst;
    if (row < M_TOK) {
      src = x + (size_t)row * D_;
      dst = xpack + (size_t)row * 1536;
    } else {
      int wr = row - M_TOK;                 // 0..2303
      int g = wr / 768, rl = wr - g * 768;
      const float* wsrc = (g == 0) ? k_w : (g == 1) ? v_w : q_w;
      src = wsrc + (size_t)rl * D_;
      dst = wpack + (size_t)wr * 1536;
    }
    src += kb * 32;
    dst += kb * 64;
#pragma unroll
    for (int u = 0; u < 8; ++u) {
      float4 f = *(const float4*)(src + u * 4);
      ushort4 h, l2; cvt4(f, h, l2);
      *(ushort4*)(dst + u * 4)      = h;
      *(ushort4*)(dst + 32 + u * 4) = l2;
    }
  }
}

// ---------------------------------------------------------------------------
// MEGA2:
//  blocks [0, QKV_TILES): fast split-bf16 GEMM qkv = x @ [k;v;q]^T (128x128
//   tile, BK=32, global_load_lds w16, pre-swizzled source chunks [m173]).
//  blocks [QKV_TILES, +32): k2 rollout chain (row 0) + top-19, 256 threads,
//   full-unrolled 197-deep MLP. Independent of the GEMM -> overlapped.
// ---------------------------------------------------------------------------
__global__ __launch_bounds__(256) void mega2_qkv_chain(const ushort* __restrict__ xpack,
                                                       const ushort* __restrict__ wpack,
                                                       const float* __restrict__ P,
                                                       const float* __restrict__ dvec,
                                                       float* __restrict__ qkv,
                                                       int* __restrict__ gidx) {
  int bid = blockIdx.x;
  if (bid < QKV_TILES) {
    __shared__ __attribute__((aligned(16))) ushort As[128 * 64];
    __shared__ __attribute__((aligned(16))) ushort Bs[128 * 64];
    int tid = threadIdx.x, lane = tid & 63, wid = tid >> 6;
    int wr = wid >> 1, wc = wid & 1;
    int lr = lane & 15, lk = lane >> 4;
    int bm = bid % 50, bn = bid / 50;            // 50 x 18

    const ushort* asrc[4];
    const ushort* bsrc[4];
    ushort* adst[4];
    ushort* bdst[4];
    int lrow = lane >> 3, cpr = lane & 7;
#pragma unroll
    for (int i = 0; i < 4; ++i) {
      int r_loc = wid * 32 + i * 8 + lrow;
      int c     = cpr ^ (r_loc & 7);
      int ga    = bm * 128 + r_loc; if (ga >= M_TOK) ga = M_TOK - 1;
      asrc[i] = xpack + (size_t)ga * 1536 + c * 8;
      bsrc[i] = wpack + (size_t)(bn * 128 + r_loc) * 1536 + c * 8;
      adst[i] = &As[(wid * 32 + i * 8) * 64];
      bdst[i] = &Bs[(wid * 32 + i * 8) * 64];
    }
    int oh = (lk ^ (lr & 7)) * 8;
    int ol = oh ^ 32;

    f32x4 acc[4][4] = {};
#pragma unroll
    for (int i = 0; i < 4; ++i) { gl_lds16(asrc[i], adst[i]); gl_lds16(bsrc[i], bdst[i]); }

    for (int kb = 0; kb < 24; ++kb) {
      __syncthreads();
      short8 afh[4], afl[4], bfh[4], bfl[4];
#pragma unroll
      for (int m = 0; m < 4; ++m) {
        const ushort* rp = &As[(wr * 64 + m * 16 + lr) * 64];
        afh[m] = *(const short8*)(rp + oh);
        afl[m] = *(const short8*)(rp + ol);
      }
#pragma unroll
      for (int n = 0; n < 4; ++n) {
        const ushort* rp = &Bs[(wc * 64 + n * 16 + lr) * 64];
        bfh[n] = *(const short8*)(rp + oh);
        bfl[n] = *(const short8*)(rp + ol);
      }
      __syncthreads();
      if (kb < 23) {
#pragma unroll
        for (int i = 0; i < 4; ++i) {
          gl_lds16(asrc[i] + (kb + 1) * 64, adst[i]);
          gl_lds16(bsrc[i] + (kb + 1) * 64, bdst[i]);
        }
      }
#pragma unroll
      for (int m = 0; m < 4; ++m)
#pragma unroll
        for (int n = 0; n < 4; ++n) {
          acc[m][n] = __builtin_amdgcn_mfma_f32_16x16x32_bf16(afh[m], bfh[n], acc[m][n], 0, 0, 0);
          acc[m][n] = __builtin_amdgcn_mfma_f32_16x16x32_bf16(afh[m], bfl[n], acc[m][n], 0, 0, 0);
          acc[m][n] = __builtin_amdgcn_mfma_f32_16x16x32_bf16(afl[m], bfh[n], acc[m][n], 0, 0, 0);
        }
    }

#pragma unroll
    for (int m = 0; m < 4; ++m) {
      int row0 = bm * 128 + wr * 64 + m * 16 + (lane >> 4) * 4;
#pragma unroll
      for (int i = 0; i < 4; ++i) {
        int row = row0 + i;
        if (row < M_TOK) {
#pragma unroll
          for (int n = 0; n < 4; ++n) {
            int col = bn * 128 + wc * 64 + n * 16 + lr;
            qkv[(size_t)row * 2304 + col] = acc[m][n][i];
          }
        }
      }
    }
  } else {
    // ----- k2: rollout chain (row 0) + top-19 -----
    int b = bid - QKV_TILES;
    __shared__ float v[200];
    int t = threadIdx.x;
    if (t < 200) {
      if (t < N1_) {
        const float* Pr = P + ((size_t)(11 * B_ + b) * N1_) * N1_;
        v[t] = Pr[t] + (t == 0 ? dvec[(11 * B_ + b) * N1_] : 0.f);
      } else {
        v[t] = 0.f;
      }
    }
    __syncthreads();

    for (int l = 10; l >= 0; --l) {
      float res = 0.f;
      if (t < N1_) {
        const float* Pc = P + ((size_t)(l * B_ + b) * N1_) * N1_ + t;
        float a[8] = {0.f, 0.f, 0.f, 0.f, 0.f, 0.f, 0.f, 0.f};
#pragma unroll
        for (int g = 0; g < 24; ++g) {
#pragma unroll
          for (int u = 0; u < 8; ++u)
            a[u] += v[g * 8 + u] * Pc[(size_t)(g * 8 + u) * N1_];
        }
#pragma unroll
        for (int u = 0; u < 5; ++u)
          a[u] += v[192 + u] * Pc[(size_t)(192 + u) * N1_];
        res = ((a[0] + a[1]) + (a[2] + a[3])) + ((a[4] + a[5]) + (a[6] + a[7]));
        res += v[t] * dvec[(l * B_ + b) * N1_ + t];       // diagonal term
      }
      __syncthreads();
      if (t < N1_) v[t] = res;
      __syncthreads();
    }

    // top-19 over v[1..196]; jax tie-break: value desc, index asc
    if (t < 64) {
      float val[4];
      int   idx[4];
#pragma unroll
      for (int c = 0; c < 4; ++c) {
        int n = t + c * 64;
        bool ok = (n < N1_ - 1);
        val[c] = ok ? v[n + 1] : -1e30f;
        idx[c] = ok ? n : (1 << 20);
      }
      for (int r = 0; r < R_; ++r) {
        float bv = val[0];
        int   bi = idx[0];
#pragma unroll
        for (int c = 1; c < 4; ++c)
          if (val[c] > bv || (val[c] == bv && idx[c] < bi)) { bv = val[c]; bi = idx[c]; }
#pragma unroll
        for (int o = 32; o; o >>= 1) {
          float ov = __shfl_xor(bv, o);
          int   oi = __shfl_xor(bi, o);
          if (ov > bv || (ov == bv && oi < bi)) { bv = ov; bi = oi; }
        }
        if (t == 0) gidx[b * R_ + r] = b * N1_ + bi + 1;
#pragma unroll
        for (int c = 0; c < 4; ++c)
          if (idx[c] == bi) val[c] = -1e30f;
      }
    }
  }
}

// ---------------------------------------------------------------------------
// K5: per-(b,h) attention (f32). K/V/Q from 2304-wide qkv; q gathered by gidx
// (projection commutes with the gather).
// ---------------------------------------------------------------------------
__global__ __launch_bounds__(256) void k5_attn(const float* __restrict__ qkv,
                                               const int* __restrict__ gidx,
                                               float* __restrict__ ctx) {
  int bh = blockIdx.x;
  int b = bh / H_, h = bh % H_;
  __shared__ float ks[N1_][68];
  __shared__ float qs[R_][64];
  __shared__ float sc[R_][200];
  __shared__ float rsum[R_];
  int t = threadIdx.x;
  int lane = t & 63, wid = t >> 6;

  const float* kbase = qkv + (size_t)(b * N1_) * 2304 + h * 64;
  for (int n = wid; n < N1_; n += 4)
    ks[n][lane] = kbase[(size_t)n * 2304 + lane];
  for (int e = t; e < R_ * 64; e += 256) {
    int r = e >> 6, d = e & 63;
    int grow = gidx[b * R_ + r];
    qs[r][d] = qkv[(size_t)grow * 2304 + 1536 + h * 64 + d];
  }
  __syncthreads();

  if (t < N1_) {
    float accr[R_];
#pragma unroll
    for (int r = 0; r < R_; ++r) accr[r] = 0.f;
#pragma unroll
    for (int d0 = 0; d0 < 4; ++d0) {
      float4 k0 = *(const float4*)&ks[t][d0 * 16 + 0];
      float4 k1 = *(const float4*)&ks[t][d0 * 16 + 4];
      float4 k2 = *(const float4*)&ks[t][d0 * 16 + 8];
      float4 k3 = *(const float4*)&ks[t][d0 * 16 + 12];
#pragma unroll
      for (int r = 0; r < R_; ++r) {
        float4 q0 = *(const float4*)&qs[r][d0 * 16 + 0];
        float4 q1 = *(const float4*)&qs[r][d0 * 16 + 4];
        float4 q2 = *(const float4*)&qs[r][d0 * 16 + 8];
        float4 q3 = *(const float4*)&qs[r][d0 * 16 + 12];
        accr[r] += k0.x * q0.x + k0.y * q0.y + k0.z * q0.z + k0.w * q0.w
                 + k1.x * q1.x + k1.y * q1.y + k1.z * q1.z + k1.w * q1.w
                 + k2.x * q2.x + k2.y * q2.y + k2.z * q2.z + k2.w * q2.w
                 + k3.x * q3.x + k3.y * q3.y + k3.z * q3.z + k3.w * q3.w;
      }
    }
#pragma unroll
    for (int r = 0; r < R_; ++r) sc[r][t] = accr[r] * 0.125f;
  }
  __syncthreads();

  for (int r = wid; r < R_; r += 4) {
    float x0 = sc[r][lane];
    float x1 = sc[r][lane + 64];
    float x2 = sc[r][lane + 128];
    bool ok3 = (lane + 192 < N1_);
    float x3 = ok3 ? sc[r][lane + 192] : -1e30f;
    float m = fmaxf(fmaxf(x0, x1), fmaxf(x2, x3));
#pragma unroll
    for (int o = 32; o; o >>= 1) m = fmaxf(m, __shfl_xor(m, o));
    float e0 = expf(x0 - m), e1 = expf(x1 - m), e2 = expf(x2 - m);
    float e3 = ok3 ? expf(x3 - m) : 0.f;
    float s = e0 + e1 + e2 + e3;
#pragma unroll
    for (int o = 32; o; o >>= 1) s += __shfl_xor(s, o);
    sc[r][lane] = e0; sc[r][lane + 64] = e1; sc[r][lane + 128] = e2;
    if (ok3) sc[r][lane + 192] = e3;
    if (lane == 0) rsum[r] = s;
  }
  __syncthreads();

  const float* vb = qkv + (size_t)(b * N1_) * 2304 + 768 + h * 64 + lane;
  int r0 = wid, r1 = wid + 4, r2 = wid + 8, r3 = wid + 12, r4 = wid + 16;
  bool has4 = (r4 < R_);
  float a0 = 0.f, a1 = 0.f, a2 = 0.f, a3 = 0.f, a4 = 0.f;
#pragma unroll 4
  for (int n = 0; n < N1_; ++n) {
    float vv = vb[(size_t)n * 2304];
    a0 += sc[r0][n] * vv;
    a1 += sc[r1][n] * vv;
    a2 += sc[r2][n] * vv;
    a3 += sc[r3][n] * vv;
    if (has4) a4 += sc[r4][n] * vv;
  }
  float* cb = ctx + (size_t)(b * R_) * D_ + h * 64 + lane;
  cb[(size_t)r0 * D_] = a0 / rsum[r0];
  cb[(size_t)r1 * D_] = a1 / rsum[r1];
  cb[(size_t)r2 * D_] = a2 / rsum[r2];
  cb[(size_t)r3 * D_] = a3 / rsum[r3];
  if (has4) cb[(size_t)r4 * D_] = a4 / rsum[r4];
}

// ---------------------------------------------------------------------------
// Slow (reg-staging) split-bf16 GEMM for the tiny proj matmul.
// ---------------------------------------------------------------------------
#define PK 40
template <int BM, int BN, int MF, int NF>
__global__ __launch_bounds__(256) void gemm_f32in(const float* __restrict__ A,
                                                  const float* __restrict__ W0,
                                                  const float* __restrict__ bias,
                                                  float* __restrict__ C,
                                                  int M, int K, int ldc) {
  __shared__ __attribute__((aligned(16))) ushort As[2][BM][PK];
  __shared__ __attribute__((aligned(16))) ushort Bs[2][BN][PK];
  constexpr int TPRA = 256 / BM;
  constexpr int EPTA = 32 / TPRA;
  constexpr int NA4  = EPTA / 4;
  constexpr int TPRB = 256 / BN;
  constexpr int EPTB = 32 / TPRB;
  constexpr int NB4  = EPTB / 4;

  int tid  = threadIdx.x;
  int lane = tid & 63, wid = tid >> 6;
  int wr = wid >> 1, wc = wid & 1;
  int lr = lane & 15, lk = lane >> 4;
  int bm = blockIdx.x, bn = blockIdx.y;

  int arow_s = tid / TPRA;
  int akoff  = (tid % TPRA) * EPTA;
  int ar = bm * BM + arow_s; if (ar >= M) ar = M - 1;
  const float* ap = A + (size_t)ar * K + akoff;

  int brow_s = tid / TPRB;
  int bkoff  = (tid % TPRB) * EPTB;
  int wrow   = bn * BN + brow_s;
  const float* wp = W0 + (size_t)wrow * K + bkoff;

  f32x4 acc[MF][NF] = {};

  float4 pa[NA4], pb[NB4];
#pragma unroll
  for (int u = 0; u < NA4; ++u) pa[u] = *(const float4*)(ap + u * 4);
#pragma unroll
  for (int u = 0; u < NB4; ++u) pb[u] = *(const float4*)(wp + u * 4);

  for (int k0 = 0; k0 < K; k0 += 32) {
#pragma unroll
    for (int u = 0; u < NA4; ++u) {
      ushort4 h, l; cvt4(pa[u], h, l);
      *(ushort4*)&As[0][arow_s][akoff + u * 4] = h;
      *(ushort4*)&As[1][arow_s][akoff + u * 4] = l;
    }
#pragma unroll
    for (int u = 0; u < NB4; ++u) {
      ushort4 h, l; cvt4(pb[u], h, l);
      *(ushort4*)&Bs[0][brow_s][bkoff + u * 4] = h;
      *(ushort4*)&Bs[1][brow_s][bkoff + u * 4] = l;
    }
    __syncthreads();

    int kn = k0 + 32;
    if (kn < K) {
#pragma unroll
      for (int u = 0; u < NA4; ++u) pa[u] = *(const float4*)(ap + kn + u * 4);
#pragma unroll
      for (int u = 0; u < NB4; ++u) pb[u] = *(const float4*)(wp + kn + u * 4);
    }

    short8 af[2][MF], bf[2][NF];
#pragma unroll
    for (int m = 0; m < MF; ++m) {
      af[0][m] = *(const short8*)&As[0][wr * (BM / 2) + m * 16 + lr][lk * 8];
      af[1][m] = *(const short8*)&As[1][wr * (BM / 2) + m * 16 + lr][lk * 8];
    }
#pragma unroll
    for (int n = 0; n < NF; ++n) {
      bf[0][n] = *(const short8*)&Bs[0][wc * (BN / 2) + n * 16 + lr][lk * 8];
      bf[1][n] = *(const short8*)&Bs[1][wc * (BN / 2) + n * 16 + lr][lk * 8];
    }
#pragma unroll
    for (int m = 0; m < MF; ++m)
#pragma unroll
      for (int n = 0; n < NF; ++n) {
        acc[m][n] = __builtin_amdgcn_mfma_f32_16x16x32_bf16(af[0][m], bf[0][n], acc[m][n], 0, 0, 0);
        acc[m][n] = __builtin_amdgcn_mfma_f32_16x16x32_bf16(af[0][m], bf[1][n], acc[m][n], 0, 0, 0);
        acc[m][n] = __builtin_amdgcn_mfma_f32_16x16x32_bf16(af[1][m], bf[0][n], acc[m][n], 0, 0, 0);
      }
    __syncthreads();
  }

#pragma unroll
  for (int m = 0; m < MF; ++m) {
    int row0 = bm * BM + wr * (BM / 2) + m * 16 + lk * 4;
#pragma unroll
    for (int i = 0; i < 4; ++i) {
      int row = row0 + i;
      if (row < M) {
#pragma unroll
        for (int n = 0; n < NF; ++n) {
          int col = bn * BN + wc * (BN / 2) + n * 16 + lr;
          float vv = acc[m][n][i];
          if (bias) vv += bias[col];
          C[(size_t)row * ldc + col] = vv;
        }
      }
    }
  }
}

// ---------------------------------------------------------------------------
extern "C" void kernel_launch(void* const* d_in, const int* in_sizes, int n_in,
                              void* d_out, int out_size, void* d_ws, size_t ws_size,
                              hipStream_t stream) {
  const float* x      = (const float*)d_in[0];
  const float* attn   = (const float*)d_in[1];
  const float* q_w    = (const float*)d_in[2];
  const float* k_w    = (const float*)d_in[3];
  const float* v_w    = (const float*)d_in[4];
  const float* proj_w = (const float*)d_in[5];
  const float* proj_b = (const float*)d_in[6];
  float* out = (float*)d_out;

  char* w = (char*)d_ws;
  auto take = [&](size_t bytes) { char* p = w; w += (bytes + 255) & ~(size_t)255; return p; };
  float*  P     = (float*)take((size_t)L_ * B_ * N1_ * N1_ * 4);   // 59.6 MB
  float*  dvec  = (float*)take((size_t)L_ * B_ * N1_ * 4);
  int*    gidx  = (int*)take(B_ * R_ * 4);
  float*  qkv   = (float*)take((size_t)M_TOK * 2304 * 4);          // 58.1 MB
  float*  ctx   = (float*)take((size_t)B_ * R_ * D_ * 4);
  ushort* xpack = (ushort*)take((size_t)M_TOK * 1536 * 2);         // 19.4 MB
  ushort* wpack = (ushort*)take((size_t)2304 * 1536 * 2);          // 7.1 MB

  // 1) MEGA1: contiguous-burst k1 (HBM stream) + bf16 hi/lo packing
  hipLaunchKernelGGL(mega1_k1_pack, dim3(MEGA1_BLOCKS), dim3(256), 0, stream,
                     attn, P, dvec, x, k_w, v_w, q_w, xpack, wpack);
  // 2) MEGA2: QKV projection GEMM (900 tiles) overlapped with rollout chain
  //    + top-19 (32 blocks) — independent work in one launch
  hipLaunchKernelGGL(mega2_qkv_chain, dim3(MEGA2_BLOCKS), dim3(256), 0, stream,
                     xpack, wpack, P, dvec, qkv, gidx);
  // 3) attention per (b,h), q gathered from qkv
  hipLaunchKernelGGL(k5_attn, dim3(B_ * H_), dim3(256), 0, stream, qkv, gidx, ctx);
  // 4) output projection + bias -> d_out
  hipLaunchKernelGGL((gemm_f32in<64, 64, 2, 2>), dim3(10, 12), dim3(256), 0, stream,
                     ctx, proj_w, proj_b, out, B_ * R_, D_, D_);
}

// Round 9
// 312.268 us; speedup vs baseline: 1.2392x; 1.2392x over previous
//
#include <hip/hip_runtime.h>
#include <math.h>

#define L_  12
#define B_  32
#define H_  12
#define N1_ 197
#define D_  768
#define R_  19
#define M_TOK (B_ * N1_)               // 6304
#define NN (N1_ * N1_)                 // 38809

#define K1_FULL_ROWS  69344            // 11 layers * 32 b * 197 rows
#define K1_ROWS       69376            // + 32 layer-11 row-0 rows
#define K1_BLOCKS     (K1_ROWS / 4)    // 17344
#define PACK_ROWS     (M_TOK + 2304)   // x rows + [k;v;q] weight rows = 8608
#define PACK_BLOCKS   ((PACK_ROWS * 12 + 255) / 256)   // 404
#define QKV_TILES     630              // 600 KV tiles + 30 gathered-q tiles

typedef __attribute__((ext_vector_type(8))) _Float16 f16x8;
typedef __attribute__((ext_vector_type(4))) float f32x4;

__device__ __forceinline__ f32x4 ld4u(const float* p) {
  f32x4 r; __builtin_memcpy(&r, p, 16); return r;
}
__device__ __forceinline__ void st4u(float* p, f32x4 v) {
  __builtin_memcpy(p, &v, 16);
}

// f32 -> fp16 bit pattern (replaces missing __half_as_ushort)
__device__ __forceinline__ ushort f2h_bits(float f) {
  _Float16 h = (_Float16)f;
  ushort u; __builtin_memcpy(&u, &h, 2); return u;
}

typedef const __attribute__((address_space(1))) void* as1_vp;
typedef __attribute__((address_space(3))) void* as3_vp;
__device__ __forceinline__ void gl_lds16(const void* g, void* s) {
  __builtin_amdgcn_global_load_lds((as1_vp)g, (as3_vp)s, 16, 0, 0);
}

// ---------------------------------------------------------------------------
// MEGA1 (R6-proven k1 + fp16 pack):
//  blocks [0, K1_BLOCKS): k1 — one wave per (l,b,i) row; lane t accumulates
//   float4 at j=4t across 12 heads; wave-reduce row sum; normalize; write P.
//   Layers 0..10 all rows; layer 11 row 0 only.
//  blocks [K1_BLOCKS, +PACK_BLOCKS): pack x and [k_w;v_w;q_w] into fp16
//   [row][12][64 fp16 = 128B] (thread per (row,kb), coalesced).
// ---------------------------------------------------------------------------
__global__ __launch_bounds__(256) void mega_k1_pack(const float* __restrict__ attn,
                                                    float* __restrict__ P,
                                                    float* __restrict__ dvec,
                                                    const float* __restrict__ x,
                                                    const float* __restrict__ k_w,
                                                    const float* __restrict__ v_w,
                                                    const float* __restrict__ q_w,
                                                    ushort* __restrict__ xpack,
                                                    ushort* __restrict__ wpack) {
  int bid = blockIdx.x;
  if (bid < K1_BLOCKS) {
    int wid = threadIdx.x >> 6;
    int t   = threadIdx.x & 63;
    int row_id = bid * 4 + wid;
    int l, b, i;
    if (row_id < K1_FULL_ROWS) {
      l = row_id / 6304;
      int rem = row_id - l * 6304;
      b = rem / 197;
      i = rem - b * 197;
    } else {
      l = 11; b = row_id - K1_FULL_ROWS; i = 0;
    }
    int lb   = l * B_ + b;
    int prow = lb * N1_ + i;
    const float* base = attn + (size_t)lb * (H_ * NN) + (size_t)i * N1_;
    f32x4 acc = {0.f, 0.f, 0.f, 0.f};
    if (t < 49) {
      const float* p = base + 4 * t;
#pragma unroll
      for (int h = 0; h < H_; ++h) acc += ld4u(p + (size_t)h * NN);
    } else if (t == 49) {
      const float* p = base + 196;
#pragma unroll
      for (int h = 0; h < H_; ++h) acc.x += p[(size_t)h * NN];
    }
    float s = (acc.x + acc.y) + (acc.z + acc.w);
#pragma unroll
    for (int o = 32; o; o >>= 1) s += __shfl_xor(s, o);
    float inv = 1.f / (s + 12.f);
    float* Pr = P + (size_t)prow * N1_;
    if (t < 49)       st4u(Pr + 4 * t, acc * inv);
    else if (t == 49) Pr[196] = acc.x * inv;
    if (t == 0) dvec[prow] = 12.f * inv;
  } else {
    int t = (bid - K1_BLOCKS) * 256 + threadIdx.x;
    if (t >= PACK_ROWS * 12) return;
    int row = t / 12, kb = t - row * 12;
    const float* src;
    ushort* dst;
    if (row < M_TOK) {
      src = x + (size_t)row * D_;
      dst = xpack + (size_t)row * 768;
    } else {
      int wr = row - M_TOK;                 // 0..2303
      int g = wr / 768, rl = wr - g * 768;
      const float* wsrc = (g == 0) ? k_w : (g == 1) ? v_w : q_w;
      src = wsrc + (size_t)rl * D_;
      dst = wpack + (size_t)wr * 768;
    }
    src += kb * 64;
    dst += kb * 64;
#pragma unroll
    for (int u = 0; u < 8; ++u) {
      float4 f = *(const float4*)(src + u * 8);
      float4 g = *(const float4*)(src + u * 8 + 4);
      f16x8 h;
      h[0] = (_Float16)f.x; h[1] = (_Float16)f.y;
      h[2] = (_Float16)f.z; h[3] = (_Float16)f.w;
      h[4] = (_Float16)g.x; h[5] = (_Float16)g.y;
      h[6] = (_Float16)g.z; h[7] = (_Float16)g.w;
      *(f16x8*)(dst + u * 8) = h;
    }
  }
}

// ---------------------------------------------------------------------------
// K2: per-batch rollout chain (row 0 only) + top-k. 1024 threads, 4-way i.
// (R6-proven)
// ---------------------------------------------------------------------------
__global__ __launch_bounds__(1024) void k2_chain_topk(const float* __restrict__ P,
                                                      const float* __restrict__ dvec,
                                                      int* __restrict__ gidx) {
  int b = blockIdx.x;
  __shared__ float v[N1_];
  __shared__ float part[4][N1_];
  int t = threadIdx.x, quar = t >> 8, j = t & 255;

  if (t < N1_) {
    const float* Pr = P + ((size_t)(11 * B_ + b) * N1_) * N1_;
    v[t] = Pr[t] + (t == 0 ? dvec[(11 * B_ + b) * N1_] : 0.f);
  }
  __syncthreads();

  for (int l = 10; l >= 0; --l) {
    if (j < N1_) {
      const float* Pc = P + ((size_t)(l * B_ + b) * N1_) * N1_ + j;
      float a[8] = {0.f, 0.f, 0.f, 0.f, 0.f, 0.f, 0.f, 0.f};
      int ibeg = (quar * N1_) / 4;
      int iend = ((quar + 1) * N1_) / 4;
      int i = ibeg;
      for (; i + 8 <= iend; i += 8) {
#pragma unroll
        for (int u = 0; u < 8; ++u)
          a[u] += v[i + u] * Pc[(size_t)(i + u) * N1_];
      }
      for (; i < iend; ++i) a[0] += v[i] * Pc[(size_t)i * N1_];
      float s = ((a[0] + a[1]) + (a[2] + a[3])) + ((a[4] + a[5]) + (a[6] + a[7]));
      if (quar == 0) s += v[j] * dvec[(l * B_ + b) * N1_ + j];
      part[quar][j] = s;
    }
    __syncthreads();
    if (t < N1_) v[t] = (part[0][t] + part[1][t]) + (part[2][t] + part[3][t]);
    __syncthreads();
  }

  if (t < 64) {
    float val[4];
    int   idx[4];
#pragma unroll
    for (int c = 0; c < 4; ++c) {
      int n = t + c * 64;
      bool ok = (n < N1_ - 1);
      val[c] = ok ? v[n + 1] : -1e30f;
      idx[c] = ok ? n : (1 << 20);
    }
    for (int r = 0; r < R_; ++r) {
      float bv = val[0];
      int   bi = idx[0];
#pragma unroll
      for (int c = 1; c < 4; ++c)
        if (val[c] > bv || (val[c] == bv && idx[c] < bi)) { bv = val[c]; bi = idx[c]; }
#pragma unroll
      for (int o = 32; o; o >>= 1) {
        float ov = __shfl_xor(bv, o);
        int   oi = __shfl_xor(bi, o);
        if (ov > bv || (ov == bv && oi < bi)) { bv = ov; bi = oi; }
      }
      if (t == 0) gidx[b * R_ + r] = b * N1_ + bi + 1;
#pragma unroll
      for (int c = 0; c < 4; ++c)
        if (idx[c] == bi) val[c] = -1e30f;
    }
  }
}

// ---------------------------------------------------------------------------
// FAST fp16 GEMM, fused KV (600 tiles) + gathered-q (30 tiles).
// 128x128 tile, BK=64 fp16 (128B/row/K-tile = 8 x 16B chunks), 12 K-steps,
// 4 waves (2x2), 4x4 16x16x32 frags, 2 MFMA per (m,n) (two 32-k slices).
// Staging & swizzle byte-identical to the R5/R6-proven path:
// global_load_lds w16, linear LDS dest, source chunk c = c' ^ (row&7) [m173];
// fragment reads at o0 = (lk^(lr&7))*8 (slice0) and o0^32 (slice1).
// ---------------------------------------------------------------------------
__global__ __launch_bounds__(256) void gemm_kvq_fast(const ushort* __restrict__ xpack,
                                                     const ushort* __restrict__ wpack,
                                                     const int* __restrict__ gidx,
                                                     float* __restrict__ kvb,
                                                     float* __restrict__ qbuf) {
  __shared__ __attribute__((aligned(16))) ushort As[128 * 64];
  __shared__ __attribute__((aligned(16))) ushort Bs[128 * 64];
  int tid = threadIdx.x, lane = tid & 63, wid = tid >> 6;
  int wr = wid >> 1, wc = wid & 1;
  int lr = lane & 15, lk = lane >> 4;

  int bid = blockIdx.x;
  int bm, wrow0, ccol0, ldc, Mrows;
  float* C;
  bool gath;
  if (bid < 600) {
    bm = bid % 50; int bn = bid / 50;
    wrow0 = bn * 128; ccol0 = bn * 128; ldc = 1536; Mrows = M_TOK;
    C = kvb; gath = false;
  } else {
    int tq = bid - 600;
    bm = tq % 5; int bn = tq / 5;
    wrow0 = 1536 + bn * 128; ccol0 = bn * 128; ldc = 768; Mrows = 608;
    C = qbuf; gath = true;
  }

  const ushort* asrc[4];
  const ushort* bsrc[4];
  ushort* adst[4];
  ushort* bdst[4];
  int lrow = lane >> 3, cpr = lane & 7;
#pragma unroll
  for (int i = 0; i < 4; ++i) {
    int r_loc = wid * 32 + i * 8 + lrow;
    int c     = cpr ^ (r_loc & 7);
    int ga    = bm * 128 + r_loc; if (ga >= Mrows) ga = Mrows - 1;
    int arow  = gath ? gidx[ga] : ga;
    asrc[i] = xpack + (size_t)arow * 768 + c * 8;
    bsrc[i] = wpack + (size_t)(wrow0 + r_loc) * 768 + c * 8;
    adst[i] = &As[(wid * 32 + i * 8) * 64];
    bdst[i] = &Bs[(wid * 32 + i * 8) * 64];
  }

  int o0 = (lk ^ (lr & 7)) * 8;      // slice 0 (k 0..31)
  int o1 = o0 ^ 32;                  // slice 1 (k 32..63)

  f32x4 acc[4][4] = {};

#pragma unroll
  for (int i = 0; i < 4; ++i) { gl_lds16(asrc[i], adst[i]); gl_lds16(bsrc[i], bdst[i]); }

  for (int kb = 0; kb < 12; ++kb) {
    __syncthreads();
    f16x8 af0[4], af1[4], bf0[4], bf1[4];
#pragma unroll
    for (int m = 0; m < 4; ++m) {
      const ushort* rp = &As[(wr * 64 + m * 16 + lr) * 64];
      af0[m] = *(const f16x8*)(rp + o0);
      af1[m] = *(const f16x8*)(rp + o1);
    }
#pragma unroll
    for (int n = 0; n < 4; ++n) {
      const ushort* rp = &Bs[(wc * 64 + n * 16 + lr) * 64];
      bf0[n] = *(const f16x8*)(rp + o0);
      bf1[n] = *(const f16x8*)(rp + o1);
    }
    __syncthreads();
    if (kb < 11) {
#pragma unroll
      for (int i = 0; i < 4; ++i) {
        gl_lds16(asrc[i] + (kb + 1) * 64, adst[i]);
        gl_lds16(bsrc[i] + (kb + 1) * 64, bdst[i]);
      }
    }
#pragma unroll
    for (int m = 0; m < 4; ++m)
#pragma unroll
      for (int n = 0; n < 4; ++n) {
        acc[m][n] = __builtin_amdgcn_mfma_f32_16x16x32_f16(af0[m], bf0[n], acc[m][n], 0, 0, 0);
        acc[m][n] = __builtin_amdgcn_mfma_f32_16x16x32_f16(af1[m], bf1[n], acc[m][n], 0, 0, 0);
      }
  }

#pragma unroll
  for (int m = 0; m < 4; ++m) {
    int row0 = bm * 128 + wr * 64 + m * 16 + (lane >> 4) * 4;
#pragma unroll
    for (int i = 0; i < 4; ++i) {
      int row = row0 + i;
      if (row < Mrows) {
#pragma unroll
        for (int n = 0; n < 4; ++n) {
          int col = ccol0 + wc * 64 + n * 16 + lr;
          C[(size_t)row * ldc + col] = acc[m][n][i];
        }
      }
    }
  }
}

// ---------------------------------------------------------------------------
// K5: per-(b,h) attention (f32). (R6-proven)
// ---------------------------------------------------------------------------
__global__ __launch_bounds__(256) void k5_attn(const float* __restrict__ kvb,
                                               const float* __restrict__ qb,
                                               float* __restrict__ ctx) {
  int bh = blockIdx.x;
  int b = bh / H_, h = bh % H_;
  __shared__ float ks[N1_][68];
  __shared__ float qs[R_][64];
  __shared__ float sc[R_][200];
  __shared__ float rsum[R_];
  int t = threadIdx.x;
  int lane = t & 63, wid = t >> 6;

  const float* kbase = kvb + (size_t)b * N1_ * 1536 + h * 64;
  for (int n = wid; n < N1_; n += 4)
    ks[n][lane] = kbase[(size_t)n * 1536 + lane];
  const float* qrow = qb + (size_t)b * R_ * D_ + h * 64;
  for (int e = t; e < R_ * 64; e += 256) {
    int r = e >> 6, d = e & 63;
    qs[r][d] = qrow[(size_t)r * D_ + d];
  }
  __syncthreads();

  if (t < N1_) {
    float accr[R_];
#pragma unroll
    for (int r = 0; r < R_; ++r) accr[r] = 0.f;
#pragma unroll
    for (int d0 = 0; d0 < 4; ++d0) {
      float4 k0 = *(const float4*)&ks[t][d0 * 16 + 0];
      float4 k1 = *(const float4*)&ks[t][d0 * 16 + 4];
      float4 k2 = *(const float4*)&ks[t][d0 * 16 + 8];
      float4 k3 = *(const float4*)&ks[t][d0 * 16 + 12];
#pragma unroll
      for (int r = 0; r < R_; ++r) {
        float4 q0 = *(const float4*)&qs[r][d0 * 16 + 0];
        float4 q1 = *(const float4*)&qs[r][d0 * 16 + 4];
        float4 q2 = *(const float4*)&qs[r][d0 * 16 + 8];
        float4 q3 = *(const float4*)&qs[r][d0 * 16 + 12];
        accr[r] += k0.x * q0.x + k0.y * q0.y + k0.z * q0.z + k0.w * q0.w
                 + k1.x * q1.x + k1.y * q1.y + k1.z * q1.z + k1.w * q1.w
                 + k2.x * q2.x + k2.y * q2.y + k2.z * q2.z + k2.w * q2.w
                 + k3.x * q3.x + k3.y * q3.y + k3.z * q3.z + k3.w * q3.w;
      }
    }
#pragma unroll
    for (int r = 0; r < R_; ++r) sc[r][t] = accr[r] * 0.125f;
  }
  __syncthreads();

  for (int r = wid; r < R_; r += 4) {
    float x0 = sc[r][lane];
    float x1 = sc[r][lane + 64];
    float x2 = sc[r][lane + 128];
    bool ok3 = (lane + 192 < N1_);
    float x3 = ok3 ? sc[r][lane + 192] : -1e30f;
    float m = fmaxf(fmaxf(x0, x1), fmaxf(x2, x3));
#pragma unroll
    for (int o = 32; o; o >>= 1) m = fmaxf(m, __shfl_xor(m, o));
    float e0 = expf(x0 - m), e1 = expf(x1 - m), e2 = expf(x2 - m);
    float e3 = ok3 ? expf(x3 - m) : 0.f;
    float s = e0 + e1 + e2 + e3;
#pragma unroll
    for (int o = 32; o; o >>= 1) s += __shfl_xor(s, o);
    sc[r][lane] = e0; sc[r][lane + 64] = e1; sc[r][lane + 128] = e2;
    if (ok3) sc[r][lane + 192] = e3;
    if (lane == 0) rsum[r] = s;
  }
  __syncthreads();

  const float* vb = kvb + (size_t)b * N1_ * 1536 + 768 + h * 64 + lane;
  int r0 = wid, r1 = wid + 4, r2 = wid + 8, r3 = wid + 12, r4 = wid + 16;
  bool has4 = (r4 < R_);
  float a0 = 0.f, a1 = 0.f, a2 = 0.f, a3 = 0.f, a4 = 0.f;
#pragma unroll 4
  for (int n = 0; n < N1_; ++n) {
    float vv = vb[(size_t)n * 1536];
    a0 += sc[r0][n] * vv;
    a1 += sc[r1][n] * vv;
    a2 += sc[r2][n] * vv;
    a3 += sc[r3][n] * vv;
    if (has4) a4 += sc[r4][n] * vv;
  }
  float* cb = ctx + (size_t)(b * R_) * D_ + h * 64 + lane;
  cb[(size_t)r0 * D_] = a0 / rsum[r0];
  cb[(size_t)r1 * D_] = a1 / rsum[r1];
  cb[(size_t)r2 * D_] = a2 / rsum[r2];
  cb[(size_t)r3 * D_] = a3 / rsum[r3];
  if (has4) cb[(size_t)r4 * D_] = a4 / rsum[r4];
}

// ---------------------------------------------------------------------------
// Slow (reg-staging) fp16 single-pass GEMM for the tiny proj matmul.
// ---------------------------------------------------------------------------
#define PK 40
template <int BM, int BN, int MF, int NF>
__global__ __launch_bounds__(256) void gemm_f32in(const float* __restrict__ A,
                                                  const float* __restrict__ W0,
                                                  const float* __restrict__ bias,
                                                  float* __restrict__ C,
                                                  int M, int K, int ldc) {
  __shared__ __attribute__((aligned(16))) ushort As[BM][PK];
  __shared__ __attribute__((aligned(16))) ushort Bs[BN][PK];
  constexpr int TPRA = 256 / BM;
  constexpr int EPTA = 32 / TPRA;
  constexpr int NA4  = EPTA / 4;
  constexpr int TPRB = 256 / BN;
  constexpr int EPTB = 32 / TPRB;
  constexpr int NB4  = EPTB / 4;

  int tid  = threadIdx.x;
  int lane = tid & 63, wid = tid >> 6;
  int wr = wid >> 1, wc = wid & 1;
  int lr = lane & 15, lk = lane >> 4;
  int bm = blockIdx.x, bn = blockIdx.y;

  int arow_s = tid / TPRA;
  int akoff  = (tid % TPRA) * EPTA;
  int ar = bm * BM + arow_s; if (ar >= M) ar = M - 1;
  const float* ap = A + (size_t)ar * K + akoff;

  int brow_s = tid / TPRB;
  int bkoff  = (tid % TPRB) * EPTB;
  int wrow   = bn * BN + brow_s;
  const float* wp = W0 + (size_t)wrow * K + bkoff;

  f32x4 acc[MF][NF] = {};

  float4 pa[NA4], pb[NB4];
#pragma unroll
  for (int u = 0; u < NA4; ++u) pa[u] = *(const float4*)(ap + u * 4);
#pragma unroll
  for (int u = 0; u < NB4; ++u) pb[u] = *(const float4*)(wp + u * 4);

  for (int k0 = 0; k0 < K; k0 += 32) {
#pragma unroll
    for (int u = 0; u < NA4; ++u) {
      ushort4 h;
      h.x = f2h_bits(pa[u].x);
      h.y = f2h_bits(pa[u].y);
      h.z = f2h_bits(pa[u].z);
      h.w = f2h_bits(pa[u].w);
      *(ushort4*)&As[arow_s][akoff + u * 4] = h;
    }
#pragma unroll
    for (int u = 0; u < NB4; ++u) {
      ushort4 h;
      h.x = f2h_bits(pb[u].x);
      h.y = f2h_bits(pb[u].y);
      h.z = f2h_bits(pb[u].z);
      h.w = f2h_bits(pb[u].w);
      *(ushort4*)&Bs[brow_s][bkoff + u * 4] = h;
    }
    __syncthreads();

    int kn = k0 + 32;
    if (kn < K) {
#pragma unroll
      for (int u = 0; u < NA4; ++u) pa[u] = *(const float4*)(ap + kn + u * 4);
#pragma unroll
      for (int u = 0; u < NB4; ++u) pb[u] = *(const float4*)(wp + kn + u * 4);
    }

    f16x8 af[MF], bf[NF];
#pragma unroll
    for (int m = 0; m < MF; ++m)
      af[m] = *(const f16x8*)&As[wr * (BM / 2) + m * 16 + lr][lk * 8];
#pragma unroll
    for (int n = 0; n < NF; ++n)
      bf[n] = *(const f16x8*)&Bs[wc * (BN / 2) + n * 16 + lr][lk * 8];
#pragma unroll
    for (int m = 0; m < MF; ++m)
#pragma unroll
      for (int n = 0; n < NF; ++n)
        acc[m][n] = __builtin_amdgcn_mfma_f32_16x16x32_f16(af[m], bf[n], acc[m][n], 0, 0, 0);
    __syncthreads();
  }

#pragma unroll
  for (int m = 0; m < MF; ++m) {
    int row0 = bm * BM + wr * (BM / 2) + m * 16 + lk * 4;
#pragma unroll
    for (int i = 0; i < 4; ++i) {
      int row = row0 + i;
      if (row < M) {
#pragma unroll
        for (int n = 0; n < NF; ++n) {
          int col = bn * BN + wc * (BN / 2) + n * 16 + lr;
          float vv = acc[m][n][i];
          if (bias) vv += bias[col];
          C[(size_t)row * ldc + col] = vv;
        }
      }
    }
  }
}

// ---------------------------------------------------------------------------
extern "C" void kernel_launch(void* const* d_in, const int* in_sizes, int n_in,
                              void* d_out, int out_size, void* d_ws, size_t ws_size,
                              hipStream_t stream) {
  const float* x      = (const float*)d_in[0];
  const float* attn   = (const float*)d_in[1];
  const float* q_w    = (const float*)d_in[2];
  const float* k_w    = (const float*)d_in[3];
  const float* v_w    = (const float*)d_in[4];
  const float* proj_w = (const float*)d_in[5];
  const float* proj_b = (const float*)d_in[6];
  float* out = (float*)d_out;

  char* w = (char*)d_ws;
  auto take = [&](size_t bytes) { char* p = w; w += (bytes + 255) & ~(size_t)255; return p; };
  float*  P     = (float*)take((size_t)L_ * B_ * N1_ * N1_ * 4);   // 59.6 MB
  float*  dvec  = (float*)take((size_t)L_ * B_ * N1_ * 4);
  int*    gidx  = (int*)take(B_ * R_ * 4);
  float*  kvb   = (float*)take((size_t)M_TOK * 1536 * 4);          // 38.7 MB
  float*  qbuf  = (float*)take((size_t)B_ * R_ * D_ * 4);
  float*  ctx   = (float*)take((size_t)B_ * R_ * D_ * 4);
  ushort* xpack = (ushort*)take((size_t)M_TOK * 768 * 2);          // 9.7 MB
  ushort* wpack = (ushort*)take((size_t)2304 * 768 * 2);           // 3.5 MB

  // 1) MEGA1: vectorized k1 (HBM stream) + fp16 packing (no LDS either side)
  hipLaunchKernelGGL(mega_k1_pack, dim3(K1_BLOCKS + PACK_BLOCKS), dim3(256), 0,
                     stream, attn, P, dvec, x, k_w, v_w, q_w, xpack, wpack);
  // 2) rollout chain (row 0) + top-19 indices
  hipLaunchKernelGGL(k2_chain_topk, dim3(B_), dim3(1024), 0, stream, P, dvec, gidx);
  // 3) fused fast fp16 GEMM: KV projection (600 tiles) + gathered-q (30 tiles)
  hipLaunchKernelGGL(gemm_kvq_fast, dim3(QKV_TILES), dim3(256), 0, stream,
                     xpack, wpack, gidx, kvb, qbuf);
  // 4) attention per (b,h)
  hipLaunchKernelGGL(k5_attn, dim3(B_ * H_), dim3(256), 0, stream, kvb, qbuf, ctx);
  // 5) output projection + bias -> d_out
  hipLaunchKernelGGL((gemm_f32in<64, 64, 2, 2>), dim3(10, 12), dim3(256), 0, stream,
                     ctx, proj_w, proj_b, out, B_ * R_, D_, D_);
}